// Round 1
// baseline (3460.696 us; speedup 1.0000x reference)
//
#include <hip/hip_runtime.h>

#ifndef __has_builtin
#define __has_builtin(x) 0
#endif

__device__ __forceinline__ float fexp2(float x) {
#if __has_builtin(__builtin_amdgcn_exp2f)
  return __builtin_amdgcn_exp2f(x);   // v_exp_f32 (2^x)
#else
  return exp2f(x);
#endif
}
__device__ __forceinline__ float flog2(float x) {
#if __has_builtin(__builtin_amdgcn_logf)
  return __builtin_amdgcn_logf(x);    // v_log_f32 (log2)
#else
  return log2f(x);
#endif
}

namespace {
constexpr int NPTS = 2048;
constexpr int NPROB = 24;          // 8 batches x {xy, xx, yy}
constexpr int WGS_PER_PROB = 32;   // 64 rows per WG
constexpr int ROWS_PER_WG = 64;
constexpr int THREADS = 256;       // 64 rows x 4 j-chunks
constexpr int NPASS = 100;         // 50 Sinkhorn iters x 2 half-passes
constexpr float LOG2E = 1.44269504088896340736f;
constexpr float KS = LOG2E / 0.0025f;                  // log2(e)/eps
constexpr float NEG_EPS_LN2 = -0.0025f * 0.69314718055994530942f; // -eps*ln2
constexpr float LOG2N = 11.0f;                         // log2(2048)
}

// One half-pass: for each target row i, compute
//   out_i = -eps*( ln(sum_j exp((phi_j - C_ij)/eps)) - ln(2048) )
// in base-2: w = KS*(phi_j - 0.5|s_j|^2) + KS*t_i.s_j - 0.5*KS*|t_i|^2
//   out_i = -eps*ln2*( max_w + log2(sum 2^(w-max)) - 11 )
__global__ void __launch_bounds__(THREADS) sink_halfpass(
    const float* __restrict__ p1, const float* __restrict__ p2,
    float* __restrict__ fpot, float* __restrict__ gpot, int t)
{
  __shared__ float4 Ls[NPTS];   // (KS*sx, KS*sy, KS*sz, KS*phi - 0.5*KS*|s|^2)

  const int w   = blockIdx.x;
  const int p   = w >> 5;          // problem 0..23
  const int blk = w & 31;          // row-block within problem
  const int b    = p / 3;
  const int kind = p - 3 * b;      // 0: xy, 1: xx, 2: yy
  const float* X = (kind == 2 ? p2 : p1) + b * (NPTS * 3);
  const float* Y = (kind == 1 ? p1 : p2) + b * (NPTS * 3);
  const bool even = (t & 1) == 0;
  // even t: f-update (targets = X rows, sources = Y with phi=g)
  // odd  t: g-update (targets = Y rows, sources = X with phi=f)
  const float* tgt = even ? X : Y;
  const float* src = even ? Y : X;
  const float* phi = (even ? gpot : fpot) + p * NPTS;
  float*      outp = (even ? fpot : gpot) + p * NPTS;

  const int tid = threadIdx.x;

  // ---- stage prescaled source data into LDS (strided j = tid + 256*i) ----
  #pragma unroll
  for (int i = 0; i < NPTS / THREADS; ++i) {
    int j = tid + THREADS * i;
    float sx = src[3 * j + 0], sy = src[3 * j + 1], sz = src[3 * j + 2];
    float ph = (t == 0) ? 0.0f : phi[j];
    float A = fmaf(KS, ph, -0.5f * KS * (sx * sx + sy * sy + sz * sz));
    Ls[j] = make_float4(KS * sx, KS * sy, KS * sz, A);
  }

  // ---- per-thread target row ----
  const int row = blk * ROWS_PER_WG + (tid >> 2);
  const int c   = tid & 3;          // j-chunk: j == c (mod 4)
  const float tx = tgt[3 * row + 0];
  const float ty = tgt[3 * row + 1];
  const float tz = tgt[3 * row + 2];
  const float Bi = -0.5f * KS * (tx * tx + ty * ty + tz * tz);
  __syncthreads();

  // ---- online logsumexp over 512 elements, 4 independent chains ----
  // chain state tracks mb = (running max) - Bi so Bi is added once at the end
  float mb0 = -1e30f, mb1 = -1e30f, mb2 = -1e30f, mb3 = -1e30f;
  float s0 = 0.f, s1 = 0.f, s2 = 0.f, s3 = 0.f;
  const float4* Lp = Ls + c;

#define STEP(Lv, mb, ss) {                                              \
    float u_ = fmaf(tx, (Lv).x, fmaf(ty, (Lv).y, fmaf(tz, (Lv).z, (Lv).w))); \
    float d_ = u_ - (mb);                                               \
    float e_ = fexp2(fminf(d_, -d_));  /* 2^(-|d|) */                   \
    bool up_ = d_ > 0.0f;                                               \
    (ss) = up_ ? fmaf((ss), e_, 1.0f) : ((ss) + e_);                    \
    (mb) = up_ ? u_ : (mb); }

  #pragma unroll 2
  for (int q = 0; q < NPTS / 16; ++q) {
    const float4* Lq = Lp + 16 * q;   // elements 16q + 4u + c
    float4 L0 = Lq[0];
    float4 L1 = Lq[4];
    float4 L2 = Lq[8];
    float4 L3 = Lq[12];
    STEP(L0, mb0, s0);
    STEP(L1, mb1, s1);
    STEP(L2, mb2, s2);
    STEP(L3, mb3, s3);
  }
#undef STEP

  // ---- merge 4 in-thread chains ----
  float M = mb0, S = s0;
  { float mo = fmaxf(M, mb1); S = fmaf(S, fexp2(M - mo), s1 * fexp2(mb1 - mo)); M = mo; }
  { float mo = fmaxf(M, mb2); S = fmaf(S, fexp2(M - mo), s2 * fexp2(mb2 - mo)); M = mo; }
  { float mo = fmaxf(M, mb3); S = fmaf(S, fexp2(M - mo), s3 * fexp2(mb3 - mo)); M = mo; }

  // ---- merge the 4 chunk lanes of each quad (butterfly) ----
  #pragma unroll
  for (int off = 1; off <= 2; off <<= 1) {
    float Mo = __shfl_xor(M, off);
    float So = __shfl_xor(S, off);
    float mo = fmaxf(M, Mo);
    S = fmaf(S, fexp2(M - mo), So * fexp2(Mo - mo));
    M = mo;
  }

  if (c == 0) {
    float lse2 = M + Bi + flog2(S);                 // log2(sum exp2(w))
    outp[row] = NEG_EPS_LN2 * (lse2 - LOG2N);       // -eps*(lse_nat - ln 2048)
  }
}

// Deterministic final reduction: mean(f)+mean(g) per problem, weighted sum.
__global__ void __launch_bounds__(THREADS) sink_finalize(
    const float* __restrict__ fpot, const float* __restrict__ gpot,
    float* __restrict__ out)
{
  __shared__ double red[THREADS];
  const int tid = threadIdx.x;
  double tot = 0.0;
  for (int p = 0; p < NPROB; ++p) {
    double acc = 0.0;
    for (int idx = tid; idx < NPTS; idx += THREADS)
      acc += (double)fpot[p * NPTS + idx] + (double)gpot[p * NPTS + idx];
    red[tid] = acc;
    __syncthreads();
    for (int st = THREADS / 2; st > 0; st >>= 1) {
      if (tid < st) red[tid] += red[tid + st];
      __syncthreads();
    }
    if (tid == 0) {
      double val = red[0] / 2048.0;                       // mean f + mean g
      double wgt = (p % 3 == 0) ? 0.125 : -0.0625;        // (1 or -1/2)/8
      tot += val * wgt;
    }
    __syncthreads();
  }
  if (tid == 0) out[0] = (float)tot;
}

extern "C" void kernel_launch(void* const* d_in, const int* in_sizes, int n_in,
                              void* d_out, int out_size, void* d_ws, size_t ws_size,
                              hipStream_t stream)
{
  const float* p1 = (const float*)d_in[0];   // pcs1 [8,2048,3] f32
  const float* p2 = (const float*)d_in[1];   // pcs2 [8,2048,3] f32
  float* fpot = (float*)d_ws;                // [24][2048]
  float* gpot = fpot + NPROB * NPTS;         // [24][2048]

  for (int t = 0; t < NPASS; ++t) {
    sink_halfpass<<<dim3(NPROB * WGS_PER_PROB), dim3(THREADS), 0, stream>>>(
        p1, p2, fpot, gpot, t);
  }
  sink_finalize<<<dim3(1), dim3(THREADS), 0, stream>>>(fpot, gpot, (float*)d_out);
}

// Round 2
// 2888.684 us; speedup vs baseline: 1.1980x; 1.1980x over previous
//
#include <hip/hip_runtime.h>

#ifndef __has_builtin
#define __has_builtin(x) 0
#endif

__device__ __forceinline__ float fexp2(float x) {
#if __has_builtin(__builtin_amdgcn_exp2f)
  return __builtin_amdgcn_exp2f(x);   // v_exp_f32 (2^x)
#else
  return exp2f(x);
#endif
}
__device__ __forceinline__ float flog2(float x) {
#if __has_builtin(__builtin_amdgcn_logf)
  return __builtin_amdgcn_logf(x);    // v_log_f32 (log2)
#else
  return log2f(x);
#endif
}

namespace {
constexpr int NPTS = 2048;
constexpr int NPROB = 24;          // 8 batches x {xy, xx, yy}
constexpr int WGS_PER_PROB = 32;   // 64 rows per WG -> grid 768 = 3 WG/CU balanced
constexpr int THREADS = 256;       // 16 row-groups x 16 source-chunks
constexpr int CHUNKS = 16;         // source chunks (lanes c = tid & 15)
constexpr int RPT = 4;             // rows per thread (register tile)
constexpr int NPASS = 100;         // 50 Sinkhorn iters x 2 half-passes
constexpr float LOG2E = 1.44269504088896340736f;
constexpr float KS = LOG2E / 0.0025f;                  // log2(e)/eps
constexpr float NEG_EPS_LN2 = -0.0025f * 0.69314718055994530942f; // -eps*ln2
constexpr float LOG2N = 11.0f;                         // log2(2048)
}

// One half-pass: for each target row i,
//   out_i = -eps*( ln(sum_j exp((phi_j - C_ij)/eps)) - ln(2048) )
// base-2: w_ij = KS*t_i.s_j + A_j (+ Bi, folded at the end),
//   A_j = KS*phi_j - 0.5*KS*|s_j|^2, Bi = -0.5*KS*|t_i|^2
// Each thread: 4 rows x 128 sources; one ds_read_b128 feeds 4 rows (reg tile);
// sources processed in quads sharing one local max (1.5 exp/elem).
__global__ void __launch_bounds__(THREADS, 4) sink_halfpass(
    const float* __restrict__ p1, const float* __restrict__ p2,
    float* __restrict__ fpot, float* __restrict__ gpot, int t)
{
  __shared__ float4 Ls[NPTS];   // (KS*sx, KS*sy, KS*sz, A_j)

  const int w   = blockIdx.x;
  const int p   = w >> 5;          // problem 0..23
  const int blk = w & 31;          // row-block within problem
  const int b    = p / 3;
  const int kind = p - 3 * b;      // 0: xy, 1: xx, 2: yy
  const float* X = (kind == 2 ? p2 : p1) + b * (NPTS * 3);
  const float* Y = (kind == 1 ? p1 : p2) + b * (NPTS * 3);
  const bool even = (t & 1) == 0;
  const float* tgt = even ? X : Y;
  const float* src = even ? Y : X;
  const float* phi = (even ? gpot : fpot) + p * NPTS;
  float*      outp = (even ? fpot : gpot) + p * NPTS;

  const int tid = threadIdx.x;

  // ---- stage prescaled source data into LDS ----
  #pragma unroll
  for (int i = 0; i < NPTS / THREADS; ++i) {
    int j = tid + THREADS * i;
    float sx = src[3 * j + 0], sy = src[3 * j + 1], sz = src[3 * j + 2];
    float ph = (t == 0) ? 0.0f : phi[j];
    float A = fmaf(KS, ph, -0.5f * KS * (sx * sx + sy * sy + sz * sz));
    Ls[j] = make_float4(KS * sx, KS * sy, KS * sz, A);
  }

  // ---- per-thread target rows (4) ----
  const int c  = tid & (CHUNKS - 1);       // source chunk
  const int rg = tid >> 4;                 // row group 0..15
  const int row0 = blk * 64 + rg * RPT;
  float tx0 = tgt[3 * (row0 + 0) + 0], ty0 = tgt[3 * (row0 + 0) + 1], tz0 = tgt[3 * (row0 + 0) + 2];
  float tx1 = tgt[3 * (row0 + 1) + 0], ty1 = tgt[3 * (row0 + 1) + 1], tz1 = tgt[3 * (row0 + 1) + 2];
  float tx2 = tgt[3 * (row0 + 2) + 0], ty2 = tgt[3 * (row0 + 2) + 1], tz2 = tgt[3 * (row0 + 2) + 2];
  float tx3 = tgt[3 * (row0 + 3) + 0], ty3 = tgt[3 * (row0 + 3) + 1], tz3 = tgt[3 * (row0 + 3) + 2];
  __syncthreads();

  float mb0 = -1e30f, mb1 = -1e30f, mb2 = -1e30f, mb3 = -1e30f;
  float s0 = 0.f, s1 = 0.f, s2 = 0.f, s3 = 0.f;
  const float4* Lp = Ls + c;

  // Quad-of-sources online LSE for one row (26 VALU + 6 exp per 4 elems)
#define QSTEP(tx, ty, tz, mb, ss) {                                          \
    float u0_ = fmaf(tx, L0.x, fmaf(ty, L0.y, fmaf(tz, L0.z, L0.w)));        \
    float u1_ = fmaf(tx, L1.x, fmaf(ty, L1.y, fmaf(tz, L1.z, L1.w)));        \
    float u2_ = fmaf(tx, L2.x, fmaf(ty, L2.y, fmaf(tz, L2.z, L2.w)));        \
    float u3_ = fmaf(tx, L3.x, fmaf(ty, L3.y, fmaf(tz, L3.z, L3.w)));        \
    float m_  = fmaxf(fmaxf(u0_, u1_), fmaxf(u2_, u3_));                     \
    float es_ = (fexp2(u0_ - m_) + fexp2(u1_ - m_))                          \
              + (fexp2(u2_ - m_) + fexp2(u3_ - m_));                         \
    float mo_ = fmaxf(mb, m_);                                               \
    (ss) = fmaf((ss), fexp2((mb) - mo_), es_ * fexp2(m_ - mo_));             \
    (mb) = mo_; }

  // 128 sources per thread, in 32 quads; each quad's 4 loads feed 4 rows.
  #pragma unroll 2
  for (int q = 0; q < NPTS / (CHUNKS * 4); ++q) {
    const float4* Lq = Lp + 64 * q;       // j = 16*(4q+k) + c
    float4 L0 = Lq[0];
    float4 L1 = Lq[16];
    float4 L2 = Lq[32];
    float4 L3 = Lq[48];
    QSTEP(tx0, ty0, tz0, mb0, s0);
    QSTEP(tx1, ty1, tz1, mb1, s1);
    QSTEP(tx2, ty2, tz2, mb2, s2);
    QSTEP(tx3, ty3, tz3, mb3, s3);
  }
#undef QSTEP

  // ---- merge the 16 chunk lanes (butterfly within each 16-lane group) ----
#define LMERGE(mb, ss) {                                                     \
    float Mo_ = __shfl_xor((mb), off);                                       \
    float So_ = __shfl_xor((ss), off);                                       \
    float mo_ = fmaxf((mb), Mo_);                                            \
    (ss) = fmaf((ss), fexp2((mb) - mo_), So_ * fexp2(Mo_ - mo_));            \
    (mb) = mo_; }

  #pragma unroll
  for (int off = 1; off <= 8; off <<= 1) {
    LMERGE(mb0, s0);
    LMERGE(mb1, s1);
    LMERGE(mb2, s2);
    LMERGE(mb3, s3);
  }
#undef LMERGE

  if (c == 0) {
    float B0 = -0.5f * KS * (tx0 * tx0 + ty0 * ty0 + tz0 * tz0);
    float B1 = -0.5f * KS * (tx1 * tx1 + ty1 * ty1 + tz1 * tz1);
    float B2 = -0.5f * KS * (tx2 * tx2 + ty2 * ty2 + tz2 * tz2);
    float B3 = -0.5f * KS * (tx3 * tx3 + ty3 * ty3 + tz3 * tz3);
    outp[row0 + 0] = NEG_EPS_LN2 * (mb0 + B0 + flog2(s0) - LOG2N);
    outp[row0 + 1] = NEG_EPS_LN2 * (mb1 + B1 + flog2(s1) - LOG2N);
    outp[row0 + 2] = NEG_EPS_LN2 * (mb2 + B2 + flog2(s2) - LOG2N);
    outp[row0 + 3] = NEG_EPS_LN2 * (mb3 + B3 + flog2(s3) - LOG2N);
  }
}

// Deterministic final reduction over the concatenated [fpot|gpot] array.
// weight(elem in problem p) = (p%3==0 ? 1 : -0.5), result /= 8*2048.
__global__ void __launch_bounds__(1024) sink_finalize(
    const float* __restrict__ pot, float* __restrict__ out)
{
  __shared__ double red[1024];
  const int tid = threadIdx.x;
  const int TOT = 2 * NPROB * NPTS;
  double acc = 0.0;
  for (int idx = tid; idx < TOT; idx += 1024) {
    int kind = (idx >> 11) % 3;        // (24+p)%3 == p%3 since 3|24
    double wgt = (kind == 0) ? 1.0 : -0.5;
    acc += wgt * (double)pot[idx];
  }
  red[tid] = acc;
  __syncthreads();
  for (int st = 512; st > 0; st >>= 1) {
    if (tid < st) red[tid] += red[tid + st];
    __syncthreads();
  }
  if (tid == 0) out[0] = (float)(red[0] / (8.0 * 2048.0));
}

extern "C" void kernel_launch(void* const* d_in, const int* in_sizes, int n_in,
                              void* d_out, int out_size, void* d_ws, size_t ws_size,
                              hipStream_t stream)
{
  const float* p1 = (const float*)d_in[0];   // pcs1 [8,2048,3] f32
  const float* p2 = (const float*)d_in[1];   // pcs2 [8,2048,3] f32
  float* fpot = (float*)d_ws;                // [24][2048]
  float* gpot = fpot + NPROB * NPTS;         // [24][2048] (contiguous after fpot)

  for (int t = 0; t < NPASS; ++t) {
    sink_halfpass<<<dim3(NPROB * WGS_PER_PROB), dim3(THREADS), 0, stream>>>(
        p1, p2, fpot, gpot, t);
  }
  sink_finalize<<<dim3(1), dim3(1024), 0, stream>>>(fpot, (float*)d_out);
}